// Round 1
// baseline (441.248 us; speedup 1.0000x reference)
//
#include <hip/hip_runtime.h>
#include <math.h>

#define NN 100000
#define NE 1600000
#define NBUK 391           // ceil(NN/256)
#define NPAD (NBUK * 256)  // 100096 padded node counters

typedef __attribute__((ext_vector_type(8))) short bf16x8;
typedef __attribute__((ext_vector_type(4))) float f32x4;

#define MFMA(A, B, C) __builtin_amdgcn_mfma_f32_16x16x32_bf16(A, B, C, 0, 0, 0)

__device__ __forceinline__ float sigm(float z) { return 1.0f / (1.0f + expf(-z)); }

// Split fp32 into two truncated bf16 halves: v ~= hi + lo, |err| <~ 2^-16 |v|.
__device__ __forceinline__ void split1(float v, unsigned short* hi, unsigned short* lo) {
  unsigned u = __float_as_uint(v);
  *hi = (unsigned short)(u >> 16);
  float hf = __uint_as_float(u & 0xFFFF0000u);
  float lf = v - hf;
  *lo = (unsigned short)(__float_as_uint(lf) >> 16);
}

__device__ __forceinline__ void split8(const float* f, bf16x8* hi, bf16x8* lo) {
#pragma unroll
  for (int j = 0; j < 8; ++j) {
    unsigned short h, l;
    split1(f[j], &h, &l);
    (*hi)[j] = (short)h;
    (*lo)[j] = (short)l;
  }
}

__device__ __forceinline__ bf16x8 as_bf16x8(uint4 q) {
  union { uint4 q; bf16x8 v; } u;
  u.q = q;
  return u.v;
}

__device__ __forceinline__ void load8(const float4* p, int idx4, float* f) {
  float4 a = p[idx4];
  float4 b = p[idx4 + 1];
  f[0] = a.x; f[1] = a.y; f[2] = a.z; f[3] = a.w;
  f[4] = b.x; f[5] = b.y; f[6] = b.z; f[7] = b.w;
}

// ---- Direct-scatter CSR build (R11): global atomics at L2 replace the
// bucket-histogram -> bucket-scatter -> in-bucket LDS sort pipeline, which
// touched colw 12.8MB x4 and was ~165us of the 243us total. colw is now
// written exactly once, and ew*dis[col] is pre-multiplied so k_fused loses
// one dependent random load per edge. ----

// k_init: zero per-node counters + build MFMA B-fragments + fused bias.
struct InitParams {
  int* cnt;
  float* deg;
  const float* W[4];
  const float* T0[4];
  const float* T1[4];
  const float* b[4];
  const float* cb[4];
  uint4* fh;
  uint4* fl;
  float* bias;  // [128] b+cb concatenated per gate
};

__global__ __launch_bounds__(512) void k_init(InitParams pp) {
  int idx = blockIdx.x * 512 + threadIdx.x;
  int stride = gridDim.x * 512;
  for (int i = idx; i < NPAD; i += stride) {
    pp.cnt[i] = 0;
    pp.deg[i] = 0.0f;
  }
  // Fragment prep: entry = T*64 + lane, 2048 total.
  // Tiles T: 0..15 x-W (K=64), 16..23 theta0, 24..31 theta1.
  // Fragment layout: B[k = quad*8+j][n = (T&7)*16 + (lane&15)].
  if (idx < 2048) {
    int T = idx >> 6;
    int lane = idx & 63;
    int ncol = ((T & 7) * 16) + (lane & 15);
    int g = ncol >> 5;
    int c = ncol & 31;
    int kq = (lane >> 4) * 8;
    const float* mat;
    int kbase;
    if (T < 16) { mat = pp.W[g]; kbase = (T >> 3) * 32 + kq; }
    else if (T < 24) { mat = pp.T0[g]; kbase = kq; }
    else { mat = pp.T1[g]; kbase = kq; }
    unsigned hw[4], lw[4];
#pragma unroll
    for (int jj = 0; jj < 4; ++jj) {
      unsigned short h0, l0, h1, l1;
      split1(mat[(kbase + 2 * jj) * 32 + c], &h0, &l0);
      split1(mat[(kbase + 2 * jj + 1) * 32 + c], &h1, &l1);
      hw[jj] = (unsigned)h0 | ((unsigned)h1 << 16);
      lw[jj] = (unsigned)l0 | ((unsigned)l1 << 16);
    }
    pp.fh[idx] = make_uint4(hw[0], hw[1], hw[2], hw[3]);
    pp.fl[idx] = make_uint4(lw[0], lw[1], lw[2], lw[3]);
  }
  if (idx < 128) {
    int g = idx >> 5;
    int c = idx & 31;
    pp.bias[idx] = pp.b[g][c] + pp.cb[g][c];
  }
}

// k_hist: per-node edge count + weighted degree via device-scope atomics.
__global__ __launch_bounds__(256) void k_hist(const int* __restrict__ row,
                                              const float* __restrict__ ew,
                                              int* __restrict__ cnt,
                                              float* __restrict__ deg) {
  int stride = gridDim.x * 256;
  for (int e = blockIdx.x * 256 + threadIdx.x; e < NE; e += stride) {
    int r = row[e];
    atomicAdd(&cnt[r], 1);
    atomicAdd(&deg[r], ew[e]);
  }
}

// k_scan_a: per-block local exclusive scan of cnt (in place -> cursor),
// block totals to btot, and dis = rsqrt(deg). Per-thread read-then-write of
// its own index only, so in-place is safe.
__global__ __launch_bounds__(256) void k_scan_a(const float* __restrict__ deg,
                                                float* __restrict__ dis,
                                                int* __restrict__ cursor,
                                                int* __restrict__ btot) {
  __shared__ int s[256];
  int b = blockIdx.x;
  int t = threadIdx.x;
  int n = b * 256 + t;
  int v = cursor[n];  // counts (zero-padded past NN)
  float dg = deg[n];
  if (n < NN) dis[n] = dg > 0.0f ? rsqrtf(dg) : 0.0f;
  s[t] = v;
  __syncthreads();
  for (int o = 1; o < 256; o <<= 1) {
    int a = (t >= o) ? s[t - o] : 0;
    __syncthreads();
    s[t] += a;
    __syncthreads();
  }
  cursor[n] = s[t] - v;  // local exclusive
  if (t == 255) btot[b] = s[255];
}

// k_scan_c: each block sums btot[0..b) itself (391 ints, trivial) and adds
// the base to its 256 cursors -> global exclusive row starts.
__global__ __launch_bounds__(256) void k_scan_c(const int* __restrict__ btot,
                                                int* __restrict__ cursor) {
  __shared__ int s[256];
  int b = blockIdx.x;
  int t = threadIdx.x;
  int acc = 0;
  for (int j = t; j < b; j += 256) acc += btot[j];
  s[t] = acc;
  __syncthreads();
  for (int o = 128; o > 0; o >>= 1) {
    if (t < o) s[t] += s[t + o];
    __syncthreads();
  }
  cursor[b * 256 + t] += s[0];
}

// k_scatter: slot = returning atomic on cursor[row]; store {col, ew*dis[col]}.
// After this kernel cursor[n] == end of row n == start of row n+1.
__global__ __launch_bounds__(256) void k_scatter(const int* __restrict__ row,
                                                 const int* __restrict__ col,
                                                 const float* __restrict__ ew,
                                                 const float* __restrict__ dis,
                                                 int* __restrict__ cursor,
                                                 int2* __restrict__ colw) {
  int stride = gridDim.x * 256;
  for (int e = blockIdx.x * 256 + threadIdx.x; e < NE; e += stride) {
    int r = row[e];
    int c = col[e];
    float w = ew[e] * dis[c];
    int slot = atomicAdd(&cursor[r], 1);
    colw[slot] = make_int2(c, __float_as_int(w));
  }
}

// ---- Fused aggregation + MFMA gates kernel ----
// One wave per 16 nodes. Phase A: lane (mr,quad) walks node m0+mr's CSR list
// accumulating sum(w * h[c][quad*8+j]) for j=0..7 — this IS the MFMA
// A-fragment layout. R11: weights are pre-normalized (no dis[c] load), and
// the gather runs 4 independent h-row fetches in flight with colw prefetched
// one group ahead (was 2 chains, latency-bound at MfmaUtil 4.5%/VALU 25%).
struct FusedParams {
  const float4* x4;    // [N][16]
  const float4* h4;    // [N][8]
  const float* cst;    // [N][32]
  const int* cursor;   // [N] row ends; start(m) = cursor[m-1] (0 for m=0)
  const int2* colw;    // [E] row-grouped {col, ew*dis[col]}
  const float* dis;    // [N]
  const uint4* fh;
  const uint4* fl;
  const float* bias;   // [128]
  const float* wlin;   // [32]
  const float* blin;   // [1]
  float* out;          // [N]
};

__device__ __forceinline__ void accrow(const FusedParams& p, int quad, int2 cw,
                                       float* acc) {
  const float4* hp = p.h4 + (cw.x * 8 + quad * 2);
  float4 a0 = hp[0], a1 = hp[1];
  float w = __int_as_float(cw.y);
  acc[0] = fmaf(w, a0.x, acc[0]); acc[1] = fmaf(w, a0.y, acc[1]);
  acc[2] = fmaf(w, a0.z, acc[2]); acc[3] = fmaf(w, a0.w, acc[3]);
  acc[4] = fmaf(w, a1.x, acc[4]); acc[5] = fmaf(w, a1.y, acc[5]);
  acc[6] = fmaf(w, a1.z, acc[6]); acc[7] = fmaf(w, a1.w, acc[7]);
}

__global__ __launch_bounds__(256) void k_fused(FusedParams p) {
  const int lane = threadIdx.x & 63;
  const int wv = threadIdx.x >> 6;
  const int m0 = blockIdx.x * 64 + wv * 16;
  const int mr = lane & 15;
  const int quad = lane >> 4;
  int m = m0 + mr;
  if (m >= NN) m = NN - 1;

  // Dense A inputs: x (K=64) and h (K=32), split to bf16 hi/lo.
  bf16x8 xh[2], xl[2], hh, hl, gh, gl;
  float f[8];
#pragma unroll
  for (int kt = 0; kt < 2; ++kt) {
    load8(p.x4, (m * 64 + kt * 32 + quad * 8) >> 2, f);
    split8(f, &xh[kt], &xl[kt]);
  }
  load8(p.h4, (m * 32 + quad * 8) >> 2, f);
  split8(f, &hh, &hl);

  // Phase A: CSR gather directly into A-fragment registers.
  float fa[8] = {0.f, 0.f, 0.f, 0.f, 0.f, 0.f, 0.f, 0.f};
  float fb[8] = {0.f, 0.f, 0.f, 0.f, 0.f, 0.f, 0.f, 0.f};
  {
    int end = p.cursor[m];
    int s0 = (m == 0) ? 0 : p.cursor[m - 1];
    int rem = end - s0;
    const int2* ep = p.colw + s0;
    int i = 0;
    if (rem >= 4) {
      int2 w0 = ep[0], w1 = ep[1], w2 = ep[2], w3 = ep[3];
      for (i = 4; i + 3 < rem; i += 4) {
        // 4 independent h-row fetches in flight.
        const float4* h0 = p.h4 + (w0.x * 8 + quad * 2);
        const float4* h1 = p.h4 + (w1.x * 8 + quad * 2);
        const float4* h2 = p.h4 + (w2.x * 8 + quad * 2);
        const float4* h3 = p.h4 + (w3.x * 8 + quad * 2);
        float4 a0 = h0[0], a1 = h0[1];
        float4 b0 = h1[0], b1 = h1[1];
        float4 c0 = h2[0], c1 = h2[1];
        float4 d0 = h3[0], d1 = h3[1];
        float f0 = __int_as_float(w0.y), f1 = __int_as_float(w1.y);
        float f2 = __int_as_float(w2.y), f3 = __int_as_float(w3.y);
        // Prefetch next colw group while h loads are in flight.
        w0 = ep[i]; w1 = ep[i + 1]; w2 = ep[i + 2]; w3 = ep[i + 3];
        fa[0] = fmaf(f0, a0.x, fa[0]); fa[1] = fmaf(f0, a0.y, fa[1]);
        fa[2] = fmaf(f0, a0.z, fa[2]); fa[3] = fmaf(f0, a0.w, fa[3]);
        fa[4] = fmaf(f0, a1.x, fa[4]); fa[5] = fmaf(f0, a1.y, fa[5]);
        fa[6] = fmaf(f0, a1.z, fa[6]); fa[7] = fmaf(f0, a1.w, fa[7]);
        fb[0] = fmaf(f1, b0.x, fb[0]); fb[1] = fmaf(f1, b0.y, fb[1]);
        fb[2] = fmaf(f1, b0.z, fb[2]); fb[3] = fmaf(f1, b0.w, fb[3]);
        fb[4] = fmaf(f1, b1.x, fb[4]); fb[5] = fmaf(f1, b1.y, fb[5]);
        fb[6] = fmaf(f1, b1.z, fb[6]); fb[7] = fmaf(f1, b1.w, fb[7]);
        fa[0] = fmaf(f2, c0.x, fa[0]); fa[1] = fmaf(f2, c0.y, fa[1]);
        fa[2] = fmaf(f2, c0.z, fa[2]); fa[3] = fmaf(f2, c0.w, fa[3]);
        fa[4] = fmaf(f2, c1.x, fa[4]); fa[5] = fmaf(f2, c1.y, fa[5]);
        fa[6] = fmaf(f2, c1.z, fa[6]); fa[7] = fmaf(f2, c1.w, fa[7]);
        fb[0] = fmaf(f3, d0.x, fb[0]); fb[1] = fmaf(f3, d0.y, fb[1]);
        fb[2] = fmaf(f3, d0.z, fb[2]); fb[3] = fmaf(f3, d0.w, fb[3]);
        fb[4] = fmaf(f3, d1.x, fb[4]); fb[5] = fmaf(f3, d1.y, fb[5]);
        fb[6] = fmaf(f3, d1.z, fb[6]); fb[7] = fmaf(f3, d1.w, fb[7]);
      }
      // Drain the prefetched group (edges [i-4, i)).
      accrow(p, quad, w0, fa);
      accrow(p, quad, w1, fb);
      accrow(p, quad, w2, fa);
      accrow(p, quad, w3, fb);
    }
    for (; i < rem; ++i) accrow(p, quad, ep[i], fa);
  }
  {
    float dn = -p.dis[m];  // negative: z -= agg @ theta1
#pragma unroll
    for (int j = 0; j < 8; ++j) f[j] = dn * (fa[j] + fb[j]);
    split8(f, &gh, &gl);
  }

  float wl0 = p.wlin[mr];
  float wl1 = p.wlin[mr + 16];
  float bl = p.blin[0];

  f32x4 acc[8];
#pragma unroll 2
  for (int nt = 0; nt < 8; ++nt) {
    float bv = p.bias[nt * 16 + mr];
    f32x4 a;
    a[0] = bv; a[1] = bv; a[2] = bv; a[3] = bv;
    bf16x8 b0h = as_bf16x8(p.fh[nt * 64 + lane]);
    bf16x8 b0l = as_bf16x8(p.fl[nt * 64 + lane]);
    bf16x8 b1h = as_bf16x8(p.fh[(8 + nt) * 64 + lane]);
    bf16x8 b1l = as_bf16x8(p.fl[(8 + nt) * 64 + lane]);
    bf16x8 t0h = as_bf16x8(p.fh[(16 + nt) * 64 + lane]);
    bf16x8 t0l = as_bf16x8(p.fl[(16 + nt) * 64 + lane]);
    bf16x8 t1h = as_bf16x8(p.fh[(24 + nt) * 64 + lane]);
    bf16x8 t1l = as_bf16x8(p.fl[(24 + nt) * 64 + lane]);
    a = MFMA(xh[0], b0h, a); a = MFMA(xh[0], b0l, a); a = MFMA(xl[0], b0h, a);
    a = MFMA(xh[1], b1h, a); a = MFMA(xh[1], b1l, a); a = MFMA(xl[1], b1h, a);
    a = MFMA(hh, t0h, a);    a = MFMA(hh, t0l, a);    a = MFMA(hl, t0h, a);
    a = MFMA(gh, t1h, a);    a = MFMA(gh, t1l, a);    a = MFMA(gl, t1h, a);
    acc[nt] = a;
  }

  // Epilogue: lane holds cols mr (tile 2g) and mr+16 (tile 2g+1) of gate g,
  // rows quad*4+r. All four gates' z in-lane.
#pragma unroll
  for (int r = 0; r < 4; ++r) {
    int node = m0 + quad * 4 + r;
    int nc = node < NN ? node : NN - 1;
    float c0 = p.cst[nc * 32 + mr];
    float c1 = p.cst[nc * 32 + 16 + mr];
    float I0 = sigm(acc[0][r]), I1 = sigm(acc[1][r]);
    float F0 = sigm(acc[2][r]), F1 = sigm(acc[3][r]);
    float T0 = tanhf(acc[4][r]), T1 = tanhf(acc[5][r]);
    float O0 = sigm(acc[6][r]), O1 = sigm(acc[7][r]);
    float C0 = fmaf(F0, c0, I0 * T0);
    float C1 = fmaf(F1, c1, I1 * T1);
    float H0 = O0 * tanhf(C0);
    float H1 = O1 * tanhf(C1);
    float part = fmaf(fmaxf(H0, 0.f), wl0, fmaxf(H1, 0.f) * wl1);
#pragma unroll
    for (int s = 1; s < 16; s <<= 1) part += __shfl_xor(part, s, 64);
    if (mr == 0 && node < NN) p.out[node] = part + bl;
  }
}

extern "C" void kernel_launch(void* const* d_in, const int* in_sizes, int n_in,
                              void* d_out, int out_size, void* d_ws, size_t ws_size,
                              hipStream_t stream) {
  const float* x = (const float*)d_in[0];
  const int* row = (const int*)d_in[1];
  const int* col = row + NE;
  const float* ew = (const float*)d_in[2];
  const float* h = (const float*)d_in[3];
  const float* c = (const float*)d_in[4];

  // Workspace layout (4-byte units), total 13.67 MB. deg/btot are overlaid
  // under colw: both are dead before k_scatter first writes colw
  // (stream-ordered). Every word is written before it is read.
  float* ws = (float*)d_ws;
  float* dis = ws;                       // [0, 100000)
  int* cursor = (int*)(ws + 100000);     // NPAD=100096 -> [100000, 200096)
  uint4* fh = (uint4*)(ws + 200096);     // 8192 floats (16B-aligned)
  uint4* fl = (uint4*)(ws + 208288);     // 8192 floats
  float* biasws = ws + 216480;           // 128
  float* deg = ws + 216608;              // NPAD (overlaid with colw)
  int* btot = (int*)(ws + 316704);       // 391 (overlaid with colw)
  int2* colw = (int2*)(ws + 216608);     // 2*NE floats = 12.8 MB (8B-aligned)

  InitParams ip;
  ip.cnt = cursor;
  ip.deg = deg;
  for (int g = 0; g < 4; ++g) {
    ip.W[g] = (const float*)d_in[5 + 4 * g];
    ip.b[g] = (const float*)d_in[6 + 4 * g];
    ip.T0[g] = (const float*)d_in[7 + 4 * g];
    ip.T1[g] = ip.T0[g] + 1024;
    ip.cb[g] = (const float*)d_in[8 + 4 * g];
  }
  ip.fh = fh;
  ip.fl = fl;
  ip.bias = biasws;
  k_init<<<98, 512, 0, stream>>>(ip);

  k_hist<<<2048, 256, 0, stream>>>(row, ew, cursor, deg);
  k_scan_a<<<NBUK, 256, 0, stream>>>(deg, dis, cursor, btot);
  k_scan_c<<<NBUK, 256, 0, stream>>>(btot, cursor);
  k_scatter<<<2048, 256, 0, stream>>>(row, col, ew, dis, cursor, colw);

  FusedParams fp;
  fp.x4 = (const float4*)x;
  fp.h4 = (const float4*)h;
  fp.cst = c;
  fp.cursor = cursor;
  fp.colw = colw;
  fp.dis = dis;
  fp.fh = fh;
  fp.fl = fl;
  fp.bias = biasws;
  fp.wlin = (const float*)d_in[21];
  fp.blin = (const float*)d_in[22];
  fp.out = (float*)d_out;
  k_fused<<<(NN + 63) / 64, 256, 0, stream>>>(fp);
}